// Round 4
// baseline (256.820 us; speedup 1.0000x reference)
//
#include <hip/hip_runtime.h>
#include <hip/hip_cooperative_groups.h>
#include <math.h>

namespace cg = cooperative_groups;

#define NN 4096
#define INDIM 45
#define HH 44
#define NHEAD 4
#define HD 11
#define NEDGE 131072
#define CAP 128            // max allowed cols per row (deg ~ Poisson(32)+diag; 128 > +8 sigma)
#define MASKW (NN / 64)

__device__ __forceinline__ float wsum64(float v) {
    #pragma unroll
    for (int i = 32; i > 0; i >>= 1) v += __shfl_xor(v, i, 64);
    return v;
}
__device__ __forceinline__ float wmax64(float v) {
    #pragma unroll
    for (int i = 32; i > 0; i >>= 1) v = fmaxf(v, __shfl_xor(v, i, 64));
    return v;
}

// One cooperative kernel: A) zero mask + QKV proj; sync; B) edge scatter; sync;
// C) per-wave sparse attention (all 4 heads) + wave-local output projection.
__global__ void fused_all(const float* __restrict__ nf, const int* __restrict__ ei,
                          const float* __restrict__ temporal,
                          const float* __restrict__ Wp, const float* __restrict__ bp,
                          const float* __restrict__ Wq, const float* __restrict__ bq,
                          const float* __restrict__ Wk, const float* __restrict__ bk,
                          const float* __restrict__ Wv, const float* __restrict__ bv,
                          const float* __restrict__ Wo, const float* __restrict__ bo,
                          unsigned long long* __restrict__ mask,
                          float* __restrict__ Qs, float* __restrict__ Ks, float* __restrict__ Vs,
                          float* __restrict__ out, int nb) {
    const int tid = threadIdx.x;
    const int bid = blockIdx.x;
    const float scale = 0.30151134457776363f;  // 1/sqrt(11)
    const float tbmul = 9.99990000099999f;     // 1/(0.1+1e-6)

    __shared__ float xs[4][HH];
    __shared__ int cols_s[4][CAP];

    // ---------- Phase A: zero mask + fused input/QKV projection ----------
    for (int i = bid * 256 + tid; i < NN * MASKW; i += nb * 256) mask[i] = 0ull;

    const int nl = tid / HH, j = tid - nl * HH;     // valid when tid < 176
    for (int grp = bid; grp < NN / 4; grp += nb) {
        __syncthreads();                            // protect xs reuse
        if (tid < 4 * HH) {
            const float* row = nf + (size_t)(grp * 4 + nl) * INDIM;
            float a = bp[j];
            #pragma unroll
            for (int k = 0; k < INDIM; ++k) a += row[k] * Wp[k * HH + j];
            xs[nl][j] = a;
        }
        __syncthreads();
        if (tid < 4 * HH) {
            const float* row = xs[nl];
            float aq = bq[j], ak = bk[j], av = bv[j];
            #pragma unroll
            for (int k = 0; k < HH; ++k) {
                float xv = row[k];
                aq += xv * Wq[k * HH + j];
                ak += xv * Wk[k * HH + j];
                av += xv * Wv[k * HH + j];
            }
            size_t o = (size_t)(grp * 4 + nl) * HH + j;
            Qs[o] = aq; Ks[o] = ak; Vs[o] = av;
        }
    }
    cg::this_grid().sync();

    // ---------- Phase B: scatter allowed pairs (edges + diagonal) ----------
    for (int i = bid * 256 + tid; i < NEDGE; i += nb * 256) {
        int r = ei[i], c = ei[NEDGE + i];
        atomicOr(&mask[(size_t)r * MASKW + (c >> 6)], 1ull << (c & 63));
    }
    for (int i = bid * 256 + tid; i < NN; i += nb * 256) {
        atomicOr(&mask[(size_t)i * MASKW + (i >> 6)], 1ull << (i & 63));
    }
    cg::this_grid().sync();

    // ---------- Phase C: sparse attention + output projection (per wave) ----------
    const int lane = tid & 63;
    const int wv = tid >> 6;
    for (int n = bid * 4 + wv; n < NN; n += nb * 4) {
        // compact this row's allowed columns into LDS (sorted, deterministic)
        unsigned long long w = mask[(size_t)n * MASKW + lane];
        int c = __popcll(w);
        int inc = c;
        #pragma unroll
        for (int i = 1; i < 64; i <<= 1) {
            int v = __shfl_up(inc, i, 64);
            if (lane >= i) inc += v;
        }
        int off = inc - c;                 // exclusive prefix
        int deg = __shfl(inc, 63, 64);
        if (deg > CAP) deg = CAP;
        while (w) {
            int b = __builtin_ctzll(w);
            w &= w - 1;
            if (off < CAP) cols_s[wv][off] = lane * 64 + b;
            ++off;
        }
        // (intra-wave LDS produce->consume; program order + lgkmcnt suffices)

        float q[NHEAD][HD];
        const float* qp = Qs + (size_t)n * HH;
        #pragma unroll
        for (int h = 0; h < NHEAD; ++h)
            #pragma unroll
            for (int d = 0; d < HD; ++d) q[h][d] = qp[h * HD + d];

        float mcur[NHEAD], lsum[NHEAD], oacc[NHEAD][HD];
        #pragma unroll
        for (int h = 0; h < NHEAD; ++h) {
            mcur[h] = -INFINITY; lsum[h] = 0.f;
            #pragma unroll
            for (int d = 0; d < HD; ++d) oacc[h][d] = 0.f;
        }

        for (int base = 0; base < deg; base += 64) {
            const int jj = base + lane;
            const bool act = jj < deg;
            const int col = act ? cols_s[wv][jj] : 0;
            float t = temporal[((size_t)n * NN + col) * 2];   // single HBM gather per pair
            const float* kp = Ks + (size_t)col * HH;
            const float* vp = Vs + (size_t)col * HH;
            float tb = sqrtf(t * tbmul);
            #pragma unroll
            for (int h = 0; h < NHEAD; ++h) {
                float s = 0.f;
                #pragma unroll
                for (int d = 0; d < HD; ++d) s += q[h][d] * kp[h * HD + d];
                s = s * scale - tb;
                if (act) {
                    if (s > mcur[h]) {
                        float f = __expf(mcur[h] - s);
                        lsum[h] *= f;
                        #pragma unroll
                        for (int d = 0; d < HD; ++d) oacc[h][d] *= f;
                        mcur[h] = s;
                    }
                    float p = __expf(s - mcur[h]);
                    lsum[h] += p;
                    #pragma unroll
                    for (int d = 0; d < HD; ++d) oacc[h][d] += p * vp[h * HD + d];
                }
            }
        }

        // merge + fused out-projection, all wave-local (wsum64 broadcasts to all lanes)
        float a = (lane < HH) ? bo[lane] : 0.f;
        float accum = 0.f;
        float Ltot = 0.f;
        float sc[NHEAD];
        #pragma unroll
        for (int h = 0; h < NHEAD; ++h) {
            float M = wmax64(mcur[h]);
            sc[h] = (mcur[h] == -INFINITY) ? 0.f : __expf(mcur[h] - M);
            float L = wsum64(lsum[h] * sc[h]);
            float inv = 1.f / L;
            float part = 0.f;
            #pragma unroll
            for (int d = 0; d < HD; ++d) {
                float o = wsum64(oacc[h][d] * sc[h]);   // attended value, all lanes
                part += o * Wo[(h * HD + d) * HH + lane];
            }
            accum += part * inv;
            (void)Ltot;
        }
        if (lane < HH) out[(size_t)n * HH + lane] = a + accum;
    }
}

extern "C" void kernel_launch(void* const* d_in, const int* in_sizes, int n_in,
                              void* d_out, int out_size, void* d_ws, size_t ws_size,
                              hipStream_t stream) {
    const float* nf       = (const float*)d_in[0];
    const int*   ei       = (const int*)d_in[1];
    const float* temporal = (const float*)d_in[2];
    const float* Wp = (const float*)d_in[3];
    const float* bp = (const float*)d_in[4];
    const float* Wq = (const float*)d_in[5];
    const float* bq = (const float*)d_in[6];
    const float* Wk = (const float*)d_in[7];
    const float* bk = (const float*)d_in[8];
    const float* Wv = (const float*)d_in[9];
    const float* bv = (const float*)d_in[10];
    const float* Wo = (const float*)d_in[11];
    const float* bo = (const float*)d_in[12];
    float* outp = (float*)d_out;

    char* ws = (char*)d_ws;
    unsigned long long* mask = (unsigned long long*)ws;        // 2 MB
    float* Qs = (float*)(ws + (2u << 20));
    float* Ks = Qs + NN * HH;
    float* Vs = Ks + NN * HH;

    int bpc = 0;
    hipOccupancyMaxActiveBlocksPerMultiprocessor(&bpc, fused_all, 256, 0);
    if (bpc < 1) bpc = 1;
    int nb = bpc * 256;              // 256 CUs on MI355X
    if (nb > 1024) nb = 1024;        // never need more than NN/4 blocks

    void* args[] = {
        (void*)&nf, (void*)&ei, (void*)&temporal,
        (void*)&Wp, (void*)&bp, (void*)&Wq, (void*)&bq,
        (void*)&Wk, (void*)&bk, (void*)&Wv, (void*)&bv,
        (void*)&Wo, (void*)&bo,
        (void*)&mask, (void*)&Qs, (void*)&Ks, (void*)&Vs,
        (void*)&outp, (void*)&nb
    };
    hipLaunchCooperativeKernel((void*)fused_all, dim3(nb), dim3(256), args, 0, stream);
}

// Round 5
// 193.541 us; speedup vs baseline: 1.3270x; 1.3270x over previous
//
#include <hip/hip_runtime.h>
#include <hip/hip_cooperative_groups.h>
#include <math.h>

namespace cg = cooperative_groups;

#define NN 4096
#define INDIM 45
#define HH 44
#define NHEAD 4
#define HD 11
#define NEDGE 131072
#define CAP 128            // max allowed cols per row (deg ~ Poisson(32)+diag; 128 > +8 sigma)
#define MASKW (NN / 64)

__device__ __forceinline__ float wsum64(float v) {
    #pragma unroll
    for (int i = 32; i > 0; i >>= 1) v += __shfl_xor(v, i, 64);
    return v;
}
__device__ __forceinline__ float wmax64(float v) {
    #pragma unroll
    for (int i = 32; i > 0; i >>= 1) v = fmaxf(v, __shfl_xor(v, i, 64));
    return v;
}

// One cooperative kernel: A) zero mask + QKV proj; sync; B) edge scatter; sync;
// C) per-wave sparse attention (all 4 heads) + wave-local output projection.
// __launch_bounds__(256): without it the compiler capped VGPR at 64 and spilled
// the 88-float accumulator state to scratch (162 MB of spill writes, round 4).
__global__ __launch_bounds__(256)
void fused_all(const float* __restrict__ nf, const int* __restrict__ ei,
               const float* __restrict__ temporal,
               const float* __restrict__ Wp, const float* __restrict__ bp,
               const float* __restrict__ Wq, const float* __restrict__ bq,
               const float* __restrict__ Wk, const float* __restrict__ bk,
               const float* __restrict__ Wv, const float* __restrict__ bv,
               const float* __restrict__ Wo, const float* __restrict__ bo,
               unsigned long long* __restrict__ mask,
               float* __restrict__ Qs, float* __restrict__ Ks, float* __restrict__ Vs,
               float* __restrict__ out, int nb) {
    const int tid = threadIdx.x;
    const int bid = blockIdx.x;
    const float scale = 0.30151134457776363f;  // 1/sqrt(11)
    const float tbmul = 9.99990000099999f;     // 1/(0.1+1e-6)

    __shared__ float xs[4][HH];        // phase A staging
    __shared__ float qs_s[4][HH];      // phase C: per-wave query vector (broadcast reads)
    __shared__ int cols_s[4][CAP];

    // ---------- Phase A: zero mask + fused input/QKV projection ----------
    for (int i = bid * 256 + tid; i < NN * MASKW; i += nb * 256) mask[i] = 0ull;

    const int nl = tid / HH, j = tid - nl * HH;     // valid when tid < 176
    for (int grp = bid; grp < NN / 4; grp += nb) {
        __syncthreads();                            // protect xs reuse across iterations
        if (tid < 4 * HH) {
            const float* row = nf + (size_t)(grp * 4 + nl) * INDIM;
            float a = bp[j];
            #pragma unroll
            for (int k = 0; k < INDIM; ++k) a += row[k] * Wp[k * HH + j];
            xs[nl][j] = a;
        }
        __syncthreads();
        if (tid < 4 * HH) {
            const float* row = xs[nl];
            float aq = bq[j], ak = bk[j], av = bv[j];
            #pragma unroll
            for (int k = 0; k < HH; ++k) {
                float xv = row[k];
                aq += xv * Wq[k * HH + j];
                ak += xv * Wk[k * HH + j];
                av += xv * Wv[k * HH + j];
            }
            size_t o = (size_t)(grp * 4 + nl) * HH + j;
            Qs[o] = aq; Ks[o] = ak; Vs[o] = av;
        }
    }
    cg::this_grid().sync();

    // ---------- Phase B: scatter allowed pairs (edges + diagonal) ----------
    for (int i = bid * 256 + tid; i < NEDGE; i += nb * 256) {
        int r = ei[i], c = ei[NEDGE + i];
        atomicOr(&mask[(size_t)r * MASKW + (c >> 6)], 1ull << (c & 63));
    }
    for (int i = bid * 256 + tid; i < NN; i += nb * 256) {
        atomicOr(&mask[(size_t)i * MASKW + (i >> 6)], 1ull << (i & 63));
    }
    cg::this_grid().sync();

    // ---------- Phase C: sparse attention + output projection (one row per wave) ----------
    const int lane = tid & 63;
    const int wv = tid >> 6;
    for (int n = bid * 4 + wv; n < NN; n += nb * 4) {
        // stage this row's query vector in LDS (wave-local; lgkmcnt orders produce->consume)
        if (lane < HH) qs_s[wv][lane] = Qs[(size_t)n * HH + lane];

        // compact this row's allowed columns into LDS (sorted, deterministic)
        unsigned long long w = mask[(size_t)n * MASKW + lane];
        int c = __popcll(w);
        int inc = c;
        #pragma unroll
        for (int i = 1; i < 64; i <<= 1) {
            int v = __shfl_up(inc, i, 64);
            if (lane >= i) inc += v;
        }
        int off = inc - c;                 // exclusive prefix
        int deg = __shfl(inc, 63, 64);
        if (deg > CAP) deg = CAP;
        while (w) {
            int b = __builtin_ctzll(w);
            w &= w - 1;
            if (off < CAP) cols_s[wv][off] = lane * 64 + b;
            ++off;
        }

        float mcur[NHEAD], lsum[NHEAD], oacc[NHEAD][HD];
        #pragma unroll
        for (int h = 0; h < NHEAD; ++h) {
            mcur[h] = -INFINITY; lsum[h] = 0.f;
            #pragma unroll
            for (int d = 0; d < HD; ++d) oacc[h][d] = 0.f;
        }

        for (int base = 0; base < deg; base += 64) {
            const int jj = base + lane;
            const bool act = jj < deg;
            const int col = act ? cols_s[wv][jj] : 0;
            float t = temporal[((size_t)n * NN + col) * 2];   // single HBM gather per pair
            const float* kp = Ks + (size_t)col * HH;
            const float* vp = Vs + (size_t)col * HH;
            float tb = sqrtf(t * tbmul);
            #pragma unroll
            for (int h = 0; h < NHEAD; ++h) {
                float s = 0.f;
                #pragma unroll
                for (int d = 0; d < HD; ++d) s += qs_s[wv][h * HD + d] * kp[h * HD + d];
                s = s * scale - tb;
                if (act) {
                    if (s > mcur[h]) {
                        float f = __expf(mcur[h] - s);
                        lsum[h] *= f;
                        #pragma unroll
                        for (int d = 0; d < HD; ++d) oacc[h][d] *= f;
                        mcur[h] = s;
                    }
                    float p = __expf(s - mcur[h]);
                    lsum[h] += p;
                    #pragma unroll
                    for (int d = 0; d < HD; ++d) oacc[h][d] += p * vp[h * HD + d];
                }
            }
        }

        // merge + fused out-projection, all wave-local (wsum64 broadcasts to all lanes)
        float accum = (lane < HH) ? bo[lane] : 0.f;
        #pragma unroll
        for (int h = 0; h < NHEAD; ++h) {
            float M = wmax64(mcur[h]);
            float sc = (mcur[h] == -INFINITY) ? 0.f : __expf(mcur[h] - M);
            float L = wsum64(lsum[h] * sc);
            float inv = 1.f / L;
            float part = 0.f;
            #pragma unroll
            for (int d = 0; d < HD; ++d) {
                float o = wsum64(oacc[h][d] * sc);   // attended value, broadcast to all lanes
                float wcol = (lane < HH) ? Wo[(h * HD + d) * HH + lane] : 0.f;
                part += o * wcol;
            }
            accum += part * inv;
        }
        if (lane < HH) out[(size_t)n * HH + lane] = accum;
    }
}

extern "C" void kernel_launch(void* const* d_in, const int* in_sizes, int n_in,
                              void* d_out, int out_size, void* d_ws, size_t ws_size,
                              hipStream_t stream) {
    const float* nf       = (const float*)d_in[0];
    const int*   ei       = (const int*)d_in[1];
    const float* temporal = (const float*)d_in[2];
    const float* Wp = (const float*)d_in[3];
    const float* bp = (const float*)d_in[4];
    const float* Wq = (const float*)d_in[5];
    const float* bq = (const float*)d_in[6];
    const float* Wk = (const float*)d_in[7];
    const float* bk = (const float*)d_in[8];
    const float* Wv = (const float*)d_in[9];
    const float* bv = (const float*)d_in[10];
    const float* Wo = (const float*)d_in[11];
    const float* bo = (const float*)d_in[12];
    float* outp = (float*)d_out;

    char* ws = (char*)d_ws;
    unsigned long long* mask = (unsigned long long*)ws;        // 2 MB
    float* Qs = (float*)(ws + (2u << 20));
    float* Ks = Qs + NN * HH;
    float* Vs = Ks + NN * HH;

    int bpc = 0;
    hipOccupancyMaxActiveBlocksPerMultiprocessor(&bpc, fused_all, 256, 0);
    if (bpc < 1) bpc = 1;
    int nb = bpc * 256;              // 256 CUs on MI355X
    if (nb > 1024) nb = 1024;        // NN/4 rows; more blocks would idle in phase C

    void* args[] = {
        (void*)&nf, (void*)&ei, (void*)&temporal,
        (void*)&Wp, (void*)&bp, (void*)&Wq, (void*)&bq,
        (void*)&Wk, (void*)&bk, (void*)&Wv, (void*)&bv,
        (void*)&Wo, (void*)&bo,
        (void*)&mask, (void*)&Qs, (void*)&Ks, (void*)&Vs,
        (void*)&outp, (void*)&nb
    };
    hipLaunchCooperativeKernel((void*)fused_all, dim3(nb), dim3(256), args, 0, stream);
}

// Round 6
// 50.017 us; speedup vs baseline: 5.1347x; 3.8695x over previous
//
#include <hip/hip_runtime.h>
#include <math.h>

#define NN 4096
#define INDIM 45
#define HH 44
#define NHEAD 4
#define HD 11
#define NEDGE 131072
#define CAP 128            // max allowed cols per row (deg ~ Poisson(32)+diag; 128 > +16 sigma)
#define MASKW (NN / 64)
#define NPB 32             // nodes per block in proj_zero

__device__ __forceinline__ float wsum64(float v) {
    #pragma unroll
    for (int i = 32; i > 0; i >>= 1) v += __shfl_xor(v, i, 64);
    return v;
}
__device__ __forceinline__ float wmax64(float v) {
    #pragma unroll
    for (int i = 32; i > 0; i >>= 1) v = fmaxf(v, __shfl_xor(v, i, 64));
    return v;
}

// ---------------- Kernel 1: zero mask + fused input/QKV projection ----------------
// Mask zeroing is folded in here (stream order puts this before build_mask, so the
// cross-block zero->scatter dependency is satisfied by the kernel boundary).
__global__ __launch_bounds__(256)
void proj_zero(const float* __restrict__ nf,
               const float* __restrict__ Wp, const float* __restrict__ bp,
               const float* __restrict__ Wq, const float* __restrict__ bq,
               const float* __restrict__ Wk, const float* __restrict__ bk,
               const float* __restrict__ Wv, const float* __restrict__ bv,
               unsigned long long* __restrict__ mask,
               float* __restrict__ Qs, float* __restrict__ Ks, float* __restrict__ Vs) {
    const int tid = threadIdx.x;
    const int gsz = gridDim.x * 256;
    for (int i = blockIdx.x * 256 + tid; i < NN * MASKW; i += gsz) mask[i] = 0ull;

    __shared__ float xs[NPB][HH];
    const int n0 = blockIdx.x * NPB;
    for (int idx = tid; idx < NPB * HH; idx += 256) {
        int nl = idx / HH, j = idx - nl * HH;
        const float* row = nf + (size_t)(n0 + nl) * INDIM;
        float a = bp[j];
        #pragma unroll
        for (int k = 0; k < INDIM; ++k) a += row[k] * Wp[k * HH + j];
        xs[nl][j] = a;
    }
    __syncthreads();
    for (int idx = tid; idx < NPB * HH; idx += 256) {
        int nl = idx / HH, j = idx - nl * HH;
        const float* row = xs[nl];
        float aq = bq[j], ak = bk[j], av = bv[j];
        #pragma unroll
        for (int k = 0; k < HH; ++k) {
            float xv = row[k];
            aq += xv * Wq[k * HH + j];
            ak += xv * Wk[k * HH + j];
            av += xv * Wv[k * HH + j];
        }
        size_t o = (size_t)(n0 + nl) * HH + j;
        Qs[o] = aq; Ks[o] = ak; Vs[o] = av;
    }
}

// ---------------- Kernel 2: scatter allowed pairs (edges + diagonal) ----------------
__global__ __launch_bounds__(256)
void build_mask(const int* __restrict__ ei, unsigned long long* __restrict__ mask) {
    int i = blockIdx.x * blockDim.x + threadIdx.x;
    if (i < NEDGE) {
        int r = ei[i];          // query
        int c = ei[NEDGE + i];  // key
        atomicOr(&mask[(size_t)r * MASKW + (c >> 6)], 1ull << (c & 63));
    }
    if (i < NN) {
        atomicOr(&mask[(size_t)i * MASKW + (i >> 6)], 1ull << (i & 63));
    }
}

// ---------------- Kernel 3: sparse attention + fused output projection ----------------
// Block = one query row; wave 0 compacts the mask row into LDS (sorted, deterministic);
// wave h handles head h: online softmax over the ~33 allowed columns, butterfly merge,
// then threads 0..43 apply @Wo + bo.
__global__ __launch_bounds__(256)
void attn_out(const float* __restrict__ Qs, const float* __restrict__ Ks,
              const float* __restrict__ Vs, const float* __restrict__ temporal,
              const unsigned long long* __restrict__ mask,
              const float* __restrict__ Wo, const float* __restrict__ bo,
              float* __restrict__ out) {
    const int tid = threadIdx.x;
    const int lane = tid & 63;
    const int h = tid >> 6;
    const int n = blockIdx.x;
    const float scale = 0.30151134457776363f;  // 1/sqrt(11)
    const float tbmul = 9.99990000099999f;     // 1/(0.1+1e-6)

    __shared__ int cols_s[CAP];
    __shared__ int deg_s;
    __shared__ float att_s[HH];

    if (h == 0) {  // wave 0: compact this row's allowed columns
        unsigned long long w = mask[(size_t)n * MASKW + lane];
        int c = __popcll(w);
        int inc = c;
        #pragma unroll
        for (int i = 1; i < 64; i <<= 1) {
            int v = __shfl_up(inc, i, 64);
            if (lane >= i) inc += v;
        }
        int off = inc - c;                 // exclusive prefix
        int deg = __shfl(inc, 63, 64);
        while (w) {
            int b = __builtin_ctzll(w);
            w &= w - 1;
            if (off < CAP) cols_s[off] = lane * 64 + b;
            ++off;
        }
        if (lane == 0) deg_s = deg < CAP ? deg : CAP;
    }
    __syncthreads();
    const int deg = deg_s;

    float q[HD];
    #pragma unroll
    for (int d = 0; d < HD; ++d) q[d] = Qs[(size_t)n * HH + h * HD + d];

    float mcur = -INFINITY, lsum = 0.f, oacc[HD];
    #pragma unroll
    for (int d = 0; d < HD; ++d) oacc[d] = 0.f;

    for (int base = 0; base < deg; base += 64) {
        const int jj = base + lane;
        const bool act = jj < deg;
        const int col = act ? cols_s[jj] : 0;
        float t = temporal[((size_t)n * NN + col) * 2];
        const float* kp = Ks + (size_t)col * HH + h * HD;
        const float* vp = Vs + (size_t)col * HH + h * HD;
        float s = 0.f;
        #pragma unroll
        for (int d = 0; d < HD; ++d) s += q[d] * kp[d];
        s = s * scale - sqrtf(t * tbmul);
        if (act) {
            if (s > mcur) {
                float f = __expf(mcur - s);
                lsum *= f;
                #pragma unroll
                for (int d = 0; d < HD; ++d) oacc[d] *= f;
                mcur = s;
            }
            float p = __expf(s - mcur);
            lsum += p;
            #pragma unroll
            for (int d = 0; d < HD; ++d) oacc[d] += p * vp[d];
        }
    }

    // exact log-sum-exp merge across the wave
    float M = wmax64(mcur);
    float sc = (mcur == -INFINITY) ? 0.f : __expf(mcur - M);
    float L = wsum64(lsum * sc);
    float inv = 1.f / L;
    #pragma unroll
    for (int d = 0; d < HD; ++d) {
        float o = wsum64(oacc[d] * sc);
        if (lane == d) att_s[h * HD + d] = o * inv;
    }
    __syncthreads();

    if (tid < HH) {
        float a = bo[tid];
        #pragma unroll
        for (int k = 0; k < HH; ++k) a += att_s[k] * Wo[k * HH + tid];
        out[(size_t)n * HH + tid] = a;
    }
}

extern "C" void kernel_launch(void* const* d_in, const int* in_sizes, int n_in,
                              void* d_out, int out_size, void* d_ws, size_t ws_size,
                              hipStream_t stream) {
    const float* nf       = (const float*)d_in[0];
    const int*   ei       = (const int*)d_in[1];
    const float* temporal = (const float*)d_in[2];
    const float* Wp = (const float*)d_in[3];
    const float* bp = (const float*)d_in[4];
    const float* Wq = (const float*)d_in[5];
    const float* bq = (const float*)d_in[6];
    const float* Wk = (const float*)d_in[7];
    const float* bk = (const float*)d_in[8];
    const float* Wv = (const float*)d_in[9];
    const float* bv = (const float*)d_in[10];
    const float* Wo = (const float*)d_in[11];
    const float* bo = (const float*)d_in[12];
    float* outp = (float*)d_out;

    char* ws = (char*)d_ws;
    unsigned long long* mask = (unsigned long long*)ws;        // 2 MB
    float* Qs = (float*)(ws + (2u << 20));
    float* Ks = Qs + NN * HH;
    float* Vs = Ks + NN * HH;

    proj_zero<<<NN / NPB, 256, 0, stream>>>(nf, Wp, bp, Wq, bq, Wk, bk, Wv, bv,
                                            mask, Qs, Ks, Vs);
    build_mask<<<(NEDGE + 255) / 256, 256, 0, stream>>>(ei, mask);
    attn_out<<<NN, 256, 0, stream>>>(Qs, Ks, Vs, temporal, mask, Wo, bo, outp);
}